// Round 1
// baseline (958.788 us; speedup 1.0000x reference)
//
#include <hip/hip_runtime.h>

#define N_NODES 50000
#define N_EDGES 800000
// dims: IN=HID=256, OUT=2

static inline int cdiv(int a, int b) { return (a + b - 1) / b; }

// ---------------- CSR build ----------------

__global__ void k_init_cnt(int* cnt, int n) {
    int i = blockIdx.x * 256 + threadIdx.x;
    if (i < n) cnt[i] = 1;  // self-loop
}

__global__ void k_count(const int* __restrict__ edst, int* cnt, int e) {
    int i = blockIdx.x * 256 + threadIdx.x;
    if (i < e) atomicAdd(&cnt[edst[i]], 1);
}

// single-block chunked exclusive scan; also emits pos (=row_ptr copy) and dis=deg^-1/2
__global__ void k_scan(const int* __restrict__ cnt, int* __restrict__ row_ptr,
                       int* __restrict__ pos, float* __restrict__ dis, int n) {
    __shared__ int sums[256];
    int t = threadIdx.x;
    int chunk = (n + 255) / 256;
    int beg = t * chunk;
    int end = beg + chunk; if (end > n) end = n;
    if (beg > n) beg = n;
    int s = 0;
    for (int i = beg; i < end; ++i) s += cnt[i];
    sums[t] = s;
    __syncthreads();
    int x = s;
    for (int off = 1; off < 256; off <<= 1) {
        int y = 0;
        if (t >= off) y = sums[t - off];
        __syncthreads();
        x += y;
        sums[t] = x;
        __syncthreads();
    }
    int run = x - s;  // exclusive prefix of this chunk
    for (int i = beg; i < end; ++i) {
        int c = cnt[i];
        row_ptr[i] = run;
        pos[i] = run;
        dis[i] = rsqrtf((float)c);
        run += c;
    }
    if (t == 255) row_ptr[n] = run;
}

__global__ void k_fill_self(int* pos, const float* __restrict__ dis,
                            int* src_s, float* norm_s, int n) {
    int i = blockIdx.x * 256 + threadIdx.x;
    if (i < n) {
        int p = atomicAdd(&pos[i], 1);
        src_s[p] = i;
        float d = dis[i];
        norm_s[p] = d * d;
    }
}

__global__ void k_fill_edges(const int* __restrict__ esrc, const int* __restrict__ edst,
                             int* pos, const float* __restrict__ dis,
                             int* src_s, float* norm_s, int e) {
    int i = blockIdx.x * 256 + threadIdx.x;
    if (i < e) {
        int s = esrc[i], d = edst[i];
        int p = atomicAdd(&pos[d], 1);
        src_s[p] = s;
        norm_s[p] = dis[s] * dis[d];
    }
}

// ---------------- GEMM [M,256] @ [256,256] -> [M,256] ----------------

__global__ __launch_bounds__(256) void k_gemm256(const float* __restrict__ A,
                                                 const float* __restrict__ W,
                                                 float* __restrict__ C, int M) {
    __shared__ float As[16][64];  // [k][m] transposed
    __shared__ float Bs[16][64];  // [k][n]
    int t = threadIdx.x;
    int m0 = blockIdx.x * 64;
    int n0 = blockIdx.y * 64;
    int tr = t >> 4;          // 0..15 -> rows tr*4..+3
    int tc = t & 15;          // 0..15 -> cols tc*4..+3
    float acc[4][4] = {};

    int arow = t >> 2;        // 0..63
    int acol = (t & 3) * 4;   // 0,4,8,12
    int am = m0 + arow; if (am >= M) am = M - 1;  // clamp; store is guarded
    const float* Aptr = A + (size_t)am * 256 + acol;
    int brow = t >> 4;        // 0..15
    int bcol = (t & 15) * 4;  // 0..60
    const float* Wptr = W + (size_t)brow * 256 + n0 + bcol;

    for (int k0 = 0; k0 < 256; k0 += 16) {
        float4 av = *(const float4*)(Aptr + k0);
        float4 bv = *(const float4*)(Wptr + (size_t)k0 * 256);
        __syncthreads();
        As[acol + 0][arow] = av.x;
        As[acol + 1][arow] = av.y;
        As[acol + 2][arow] = av.z;
        As[acol + 3][arow] = av.w;
        *(float4*)&Bs[brow][bcol] = bv;
        __syncthreads();
#pragma unroll
        for (int k = 0; k < 16; ++k) {
            float a0 = As[k][tr * 4 + 0];
            float a1 = As[k][tr * 4 + 1];
            float a2 = As[k][tr * 4 + 2];
            float a3 = As[k][tr * 4 + 3];
            float b0 = Bs[k][tc * 4 + 0];
            float b1 = Bs[k][tc * 4 + 1];
            float b2 = Bs[k][tc * 4 + 2];
            float b3 = Bs[k][tc * 4 + 3];
            acc[0][0] += a0 * b0; acc[0][1] += a0 * b1; acc[0][2] += a0 * b2; acc[0][3] += a0 * b3;
            acc[1][0] += a1 * b0; acc[1][1] += a1 * b1; acc[1][2] += a1 * b2; acc[1][3] += a1 * b3;
            acc[2][0] += a2 * b0; acc[2][1] += a2 * b1; acc[2][2] += a2 * b2; acc[2][3] += a2 * b3;
            acc[3][0] += a3 * b0; acc[3][1] += a3 * b1; acc[3][2] += a3 * b2; acc[3][3] += a3 * b3;
        }
    }
#pragma unroll
    for (int i = 0; i < 4; ++i) {
        int m = m0 + tr * 4 + i;
        if (m < M) {
            float4 v = make_float4(acc[i][0], acc[i][1], acc[i][2], acc[i][3]);
            *(float4*)(C + (size_t)m * 256 + n0 + tc * 4) = v;
        }
    }
}

// ---------------- aggregation dim=256: out[n] = relu?(sum norm*t[src] + b) ----------------

__global__ __launch_bounds__(256) void k_agg256(const float* __restrict__ t,
                                                const int* __restrict__ row_ptr,
                                                const int* __restrict__ src_s,
                                                const float* __restrict__ norm_s,
                                                const float* __restrict__ bias,
                                                float* __restrict__ out, int n, int relu) {
    int lane = threadIdx.x & 63;
    int wave = threadIdx.x >> 6;
    int node = blockIdx.x * 4 + wave;
    if (node >= n) return;
    int beg = row_ptr[node], end = row_ptr[node + 1];
    float ax = 0.f, ay = 0.f, az = 0.f, aw = 0.f;
    int e = beg;
    for (; e + 1 < end; e += 2) {
        int s0 = src_s[e], s1 = src_s[e + 1];
        float w0 = norm_s[e], w1 = norm_s[e + 1];
        float4 v0 = *(const float4*)(t + (size_t)s0 * 256 + lane * 4);
        float4 v1 = *(const float4*)(t + (size_t)s1 * 256 + lane * 4);
        ax += w0 * v0.x + w1 * v1.x;
        ay += w0 * v0.y + w1 * v1.y;
        az += w0 * v0.z + w1 * v1.z;
        aw += w0 * v0.w + w1 * v1.w;
    }
    if (e < end) {
        int s0 = src_s[e];
        float w0 = norm_s[e];
        float4 v0 = *(const float4*)(t + (size_t)s0 * 256 + lane * 4);
        ax += w0 * v0.x; ay += w0 * v0.y; az += w0 * v0.z; aw += w0 * v0.w;
    }
    float4 b = *(const float4*)(bias + lane * 4);
    ax += b.x; ay += b.y; az += b.z; aw += b.w;
    if (relu) {
        ax = ax > 0.f ? ax : 0.f;
        ay = ay > 0.f ? ay : 0.f;
        az = az > 0.f ? az : 0.f;
        aw = aw > 0.f ? aw : 0.f;
    }
    *(float4*)(out + (size_t)node * 256 + lane * 4) = make_float4(ax, ay, az, aw);
}

// ---------------- final projection [N,256]@[256,2] (wave per row) ----------------

__global__ __launch_bounds__(256) void k_gemm_out2(const float* __restrict__ h,
                                                   const float* __restrict__ W3,
                                                   float* __restrict__ t2, int n) {
    int lane = threadIdx.x & 63;
    int wave = threadIdx.x >> 6;
    int row = blockIdx.x * 4 + wave;
    if (row >= n) return;
    float4 v = *(const float4*)(h + (size_t)row * 256 + lane * 4);
    // W3 row-major [256,2]; lane handles k = 4*lane .. 4*lane+3
    float4 w01 = *(const float4*)(W3 + lane * 8);      // (k0,j0)(k0,j1)(k1,j0)(k1,j1)
    float4 w23 = *(const float4*)(W3 + lane * 8 + 4);  // (k2,j0)(k2,j1)(k3,j0)(k3,j1)
    float s0 = v.x * w01.x + v.y * w01.z + v.z * w23.x + v.w * w23.z;
    float s1 = v.x * w01.y + v.y * w01.w + v.z * w23.y + v.w * w23.w;
#pragma unroll
    for (int off = 32; off > 0; off >>= 1) {
        s0 += __shfl_down(s0, off);
        s1 += __shfl_down(s1, off);
    }
    if (lane == 0) {
        t2[(size_t)row * 2 + 0] = s0;
        t2[(size_t)row * 2 + 1] = s1;
    }
}

__global__ void k_agg2(const float* __restrict__ t2,
                       const int* __restrict__ row_ptr,
                       const int* __restrict__ src_s,
                       const float* __restrict__ norm_s,
                       const float* __restrict__ b3,
                       float* __restrict__ out, int n) {
    int node = blockIdx.x * 256 + threadIdx.x;
    if (node >= n) return;
    int beg = row_ptr[node], end = row_ptr[node + 1];
    float a0 = 0.f, a1 = 0.f;
    for (int e = beg; e < end; ++e) {
        int s = src_s[e];
        float w = norm_s[e];
        float2 v = *(const float2*)(t2 + (size_t)s * 2);
        a0 += w * v.x;
        a1 += w * v.y;
    }
    out[(size_t)node * 2 + 0] = a0 + b3[0];
    out[(size_t)node * 2 + 1] = a1 + b3[1];
}

// ---------------- launch ----------------

extern "C" void kernel_launch(void* const* d_in, const int* in_sizes, int n_in,
                              void* d_out, int out_size, void* d_ws, size_t ws_size,
                              hipStream_t stream) {
    const int N = N_NODES, E = N_EDGES;
    const float* x  = (const float*)d_in[0];
    const int* ei   = (const int*)d_in[1];
    const int* esrc = ei;       // edge_index[0]
    const int* edst = ei + E;   // edge_index[1]
    const float* W0 = (const float*)d_in[2];
    const float* b0 = (const float*)d_in[3];
    const float* W1 = (const float*)d_in[4];
    const float* b1 = (const float*)d_in[5];
    const float* W2 = (const float*)d_in[6];
    const float* b2 = (const float*)d_in[7];
    const float* W3 = (const float*)d_in[8];
    const float* b3 = (const float*)d_in[9];
    float* out = (float*)d_out;

    // workspace carve
    float* A      = (float*)d_ws;                   // N*256
    float* B      = A + (size_t)N * 256;            // N*256
    float* t2     = B + (size_t)N * 256;            // N*2
    float* dis    = t2 + (size_t)N * 2;             // N
    float* norm_s = dis + N;                        // E+N
    int*   cnt    = (int*)(norm_s + (E + N));       // N
    int*   row_ptr= cnt + N;                        // N+1
    int*   pos    = row_ptr + (N + 1);              // N
    int*   src_s  = pos + N;                        // E+N

    // CSR build
    k_init_cnt<<<cdiv(N, 256), 256, 0, stream>>>(cnt, N);
    k_count<<<cdiv(E, 256), 256, 0, stream>>>(edst, cnt, E);
    k_scan<<<1, 256, 0, stream>>>(cnt, row_ptr, pos, dis, N);
    k_fill_self<<<cdiv(N, 256), 256, 0, stream>>>(pos, dis, src_s, norm_s, N);
    k_fill_edges<<<cdiv(E, 256), 256, 0, stream>>>(esrc, edst, pos, dis, src_s, norm_s, E);

    dim3 ggrid(cdiv(N, 64), 4);
    int agrid = cdiv(N, 4);

    // layer 0
    k_gemm256<<<ggrid, 256, 0, stream>>>(x, W0, A, N);
    k_agg256<<<agrid, 256, 0, stream>>>(A, row_ptr, src_s, norm_s, b0, B, N, 1);
    // layer 1
    k_gemm256<<<ggrid, 256, 0, stream>>>(B, W1, A, N);
    k_agg256<<<agrid, 256, 0, stream>>>(A, row_ptr, src_s, norm_s, b1, B, N, 1);
    // layer 2
    k_gemm256<<<ggrid, 256, 0, stream>>>(B, W2, A, N);
    k_agg256<<<agrid, 256, 0, stream>>>(A, row_ptr, src_s, norm_s, b2, B, N, 1);
    // layer 3 (no relu)
    k_gemm_out2<<<agrid, 256, 0, stream>>>(B, W3, t2, N);
    k_agg2<<<cdiv(N, 256), 256, 0, stream>>>(t2, row_ptr, src_s, norm_s, b3, out, N);
}

// Round 2
// 842.311 us; speedup vs baseline: 1.1383x; 1.1383x over previous
//
#include <hip/hip_runtime.h>

#define N_NODES 50000
#define N_EDGES 800000
// dims: IN=HID=256, OUT=2

static inline int cdiv(int a, int b) { return (a + b - 1) / b; }

// ---------------- CSR build ----------------

__global__ void k_init_cnt(int* cnt, int n) {
    int i = blockIdx.x * 256 + threadIdx.x;
    if (i < n) cnt[i] = 1;  // self-loop
}

__global__ void k_count(const int* __restrict__ edst, int* cnt, int e) {
    int i = blockIdx.x * 256 + threadIdx.x;
    if (i < e) atomicAdd(&cnt[edst[i]], 1);
}

// hierarchical scan: pass 1 — per-block (1024 elems) exclusive scan + block totals
__global__ __launch_bounds__(256) void k_scan1(const int* __restrict__ cnt,
                                               int* __restrict__ row_ptr,
                                               float* __restrict__ dis,
                                               int* __restrict__ blk, int n) {
    __shared__ int sums[256];
    int t = threadIdx.x;
    int base = blockIdx.x * 1024 + t * 4;
    int c0 = 0, c1 = 0, c2 = 0, c3 = 0;
    if (base + 3 < n) {
        int4 v = *(const int4*)(cnt + base);
        c0 = v.x; c1 = v.y; c2 = v.z; c3 = v.w;
    } else {
        if (base + 0 < n) c0 = cnt[base + 0];
        if (base + 1 < n) c1 = cnt[base + 1];
        if (base + 2 < n) c2 = cnt[base + 2];
        if (base + 3 < n) c3 = cnt[base + 3];
    }
    int s = c0 + c1 + c2 + c3;
    sums[t] = s;
    __syncthreads();
    int x = s;
    for (int off = 1; off < 256; off <<= 1) {
        int y = (t >= off) ? sums[t - off] : 0;
        __syncthreads();
        x += y;
        sums[t] = x;
        __syncthreads();
    }
    int excl = x - s;  // exclusive prefix within block
    if (base + 0 < n) { row_ptr[base + 0] = excl;               dis[base + 0] = rsqrtf((float)c0); }
    if (base + 1 < n) { row_ptr[base + 1] = excl + c0;          dis[base + 1] = rsqrtf((float)c1); }
    if (base + 2 < n) { row_ptr[base + 2] = excl + c0 + c1;     dis[base + 2] = rsqrtf((float)c2); }
    if (base + 3 < n) { row_ptr[base + 3] = excl + c0 + c1 + c2; dis[base + 3] = rsqrtf((float)c3); }
    if (t == 255) blk[blockIdx.x] = x;  // block total
}

// pass 2 — scan block totals (nb <= 256), write grand total to row_ptr[n]
__global__ __launch_bounds__(256) void k_scan2(int* __restrict__ blk,
                                               int* __restrict__ row_ptr_n, int nb) {
    __shared__ int sums[256];
    int t = threadIdx.x;
    int s = (t < nb) ? blk[t] : 0;
    sums[t] = s;
    __syncthreads();
    int x = s;
    for (int off = 1; off < 256; off <<= 1) {
        int y = (t >= off) ? sums[t - off] : 0;
        __syncthreads();
        x += y;
        sums[t] = x;
        __syncthreads();
    }
    if (t < nb) blk[t] = x - s;  // exclusive
    if (t == 255) row_ptr_n[0] = x;  // grand total (inclusive over all)
}

// pass 3 — add block offsets, emit pos copy
__global__ __launch_bounds__(256) void k_scan3(int* __restrict__ row_ptr,
                                               int* __restrict__ pos,
                                               const int* __restrict__ blk, int n) {
    int base = blockIdx.x * 1024 + threadIdx.x * 4;
    int off = blk[blockIdx.x];
#pragma unroll
    for (int i = 0; i < 4; ++i) {
        int idx = base + i;
        if (idx < n) {
            int v = row_ptr[idx] + off;
            row_ptr[idx] = v;
            pos[idx] = v;
        }
    }
}

__global__ void k_fill_self(int* pos, const float* __restrict__ dis,
                            int* src_s, float* norm_s, int n) {
    int i = blockIdx.x * 256 + threadIdx.x;
    if (i < n) {
        int p = atomicAdd(&pos[i], 1);
        src_s[p] = i;
        float d = dis[i];
        norm_s[p] = d * d;
    }
}

__global__ void k_fill_edges(const int* __restrict__ esrc, const int* __restrict__ edst,
                             int* pos, const float* __restrict__ dis,
                             int* src_s, float* norm_s, int e) {
    int i = blockIdx.x * 256 + threadIdx.x;
    if (i < e) {
        int s = esrc[i], d = edst[i];
        int p = atomicAdd(&pos[d], 1);
        src_s[p] = s;
        norm_s[p] = dis[s] * dis[d];
    }
}

// ---------------- GEMM [M,256] @ [256,256] -> [M,256] ----------------

__global__ __launch_bounds__(256) void k_gemm256(const float* __restrict__ A,
                                                 const float* __restrict__ W,
                                                 float* __restrict__ C, int M) {
    __shared__ float As[16][64];  // [k][m] transposed
    __shared__ float Bs[16][64];  // [k][n]
    int t = threadIdx.x;
    int m0 = blockIdx.x * 64;
    int n0 = blockIdx.y * 64;
    int tr = t >> 4;          // 0..15 -> rows tr*4..+3
    int tc = t & 15;          // 0..15 -> cols tc*4..+3
    float acc[4][4] = {};

    int arow = t >> 2;        // 0..63
    int acol = (t & 3) * 4;   // 0,4,8,12
    int am = m0 + arow; if (am >= M) am = M - 1;  // clamp; store is guarded
    const float* Aptr = A + (size_t)am * 256 + acol;
    int brow = t >> 4;        // 0..15
    int bcol = (t & 15) * 4;  // 0..60
    const float* Wptr = W + (size_t)brow * 256 + n0 + bcol;

    for (int k0 = 0; k0 < 256; k0 += 16) {
        float4 av = *(const float4*)(Aptr + k0);
        float4 bv = *(const float4*)(Wptr + (size_t)k0 * 256);
        __syncthreads();
        As[acol + 0][arow] = av.x;
        As[acol + 1][arow] = av.y;
        As[acol + 2][arow] = av.z;
        As[acol + 3][arow] = av.w;
        *(float4*)&Bs[brow][bcol] = bv;
        __syncthreads();
#pragma unroll
        for (int k = 0; k < 16; ++k) {
            float a0 = As[k][tr * 4 + 0];
            float a1 = As[k][tr * 4 + 1];
            float a2 = As[k][tr * 4 + 2];
            float a3 = As[k][tr * 4 + 3];
            float b0 = Bs[k][tc * 4 + 0];
            float b1 = Bs[k][tc * 4 + 1];
            float b2 = Bs[k][tc * 4 + 2];
            float b3 = Bs[k][tc * 4 + 3];
            acc[0][0] += a0 * b0; acc[0][1] += a0 * b1; acc[0][2] += a0 * b2; acc[0][3] += a0 * b3;
            acc[1][0] += a1 * b0; acc[1][1] += a1 * b1; acc[1][2] += a1 * b2; acc[1][3] += a1 * b3;
            acc[2][0] += a2 * b0; acc[2][1] += a2 * b1; acc[2][2] += a2 * b2; acc[2][3] += a2 * b3;
            acc[3][0] += a3 * b0; acc[3][1] += a3 * b1; acc[3][2] += a3 * b2; acc[3][3] += a3 * b3;
        }
    }
#pragma unroll
    for (int i = 0; i < 4; ++i) {
        int m = m0 + tr * 4 + i;
        if (m < M) {
            float4 v = make_float4(acc[i][0], acc[i][1], acc[i][2], acc[i][3]);
            *(float4*)(C + (size_t)m * 256 + n0 + tc * 4) = v;
        }
    }
}

// ---------------- aggregation dim=256: out[n] = relu?(sum norm*t[src] + b) ----------------

__global__ __launch_bounds__(256) void k_agg256(const float* __restrict__ t,
                                                const int* __restrict__ row_ptr,
                                                const int* __restrict__ src_s,
                                                const float* __restrict__ norm_s,
                                                const float* __restrict__ bias,
                                                float* __restrict__ out, int n, int relu) {
    int lane = threadIdx.x & 63;
    int wave = threadIdx.x >> 6;
    int node = blockIdx.x * 4 + wave;
    if (node >= n) return;
    int beg = row_ptr[node], end = row_ptr[node + 1];
    float ax = 0.f, ay = 0.f, az = 0.f, aw = 0.f;
    int e = beg;
    for (; e + 1 < end; e += 2) {
        int s0 = src_s[e], s1 = src_s[e + 1];
        float w0 = norm_s[e], w1 = norm_s[e + 1];
        float4 v0 = *(const float4*)(t + (size_t)s0 * 256 + lane * 4);
        float4 v1 = *(const float4*)(t + (size_t)s1 * 256 + lane * 4);
        ax += w0 * v0.x + w1 * v1.x;
        ay += w0 * v0.y + w1 * v1.y;
        az += w0 * v0.z + w1 * v1.z;
        aw += w0 * v0.w + w1 * v1.w;
    }
    if (e < end) {
        int s0 = src_s[e];
        float w0 = norm_s[e];
        float4 v0 = *(const float4*)(t + (size_t)s0 * 256 + lane * 4);
        ax += w0 * v0.x; ay += w0 * v0.y; az += w0 * v0.z; aw += w0 * v0.w;
    }
    float4 b = *(const float4*)(bias + lane * 4);
    ax += b.x; ay += b.y; az += b.z; aw += b.w;
    if (relu) {
        ax = ax > 0.f ? ax : 0.f;
        ay = ay > 0.f ? ay : 0.f;
        az = az > 0.f ? az : 0.f;
        aw = aw > 0.f ? aw : 0.f;
    }
    *(float4*)(out + (size_t)node * 256 + lane * 4) = make_float4(ax, ay, az, aw);
}

// ---------------- final projection [N,256]@[256,2] (wave per row) ----------------

__global__ __launch_bounds__(256) void k_gemm_out2(const float* __restrict__ h,
                                                   const float* __restrict__ W3,
                                                   float* __restrict__ t2, int n) {
    int lane = threadIdx.x & 63;
    int wave = threadIdx.x >> 6;
    int row = blockIdx.x * 4 + wave;
    if (row >= n) return;
    float4 v = *(const float4*)(h + (size_t)row * 256 + lane * 4);
    // W3 row-major [256,2]; lane handles k = 4*lane .. 4*lane+3
    float4 w01 = *(const float4*)(W3 + lane * 8);      // (k0,j0)(k0,j1)(k1,j0)(k1,j1)
    float4 w23 = *(const float4*)(W3 + lane * 8 + 4);  // (k2,j0)(k2,j1)(k3,j0)(k3,j1)
    float s0 = v.x * w01.x + v.y * w01.z + v.z * w23.x + v.w * w23.z;
    float s1 = v.x * w01.y + v.y * w01.w + v.z * w23.y + v.w * w23.w;
#pragma unroll
    for (int off = 32; off > 0; off >>= 1) {
        s0 += __shfl_down(s0, off);
        s1 += __shfl_down(s1, off);
    }
    if (lane == 0) {
        t2[(size_t)row * 2 + 0] = s0;
        t2[(size_t)row * 2 + 1] = s1;
    }
}

__global__ void k_agg2(const float* __restrict__ t2,
                       const int* __restrict__ row_ptr,
                       const int* __restrict__ src_s,
                       const float* __restrict__ norm_s,
                       const float* __restrict__ b3,
                       float* __restrict__ out, int n) {
    int node = blockIdx.x * 256 + threadIdx.x;
    if (node >= n) return;
    int beg = row_ptr[node], end = row_ptr[node + 1];
    float a0 = 0.f, a1 = 0.f;
    for (int e = beg; e < end; ++e) {
        int s = src_s[e];
        float w = norm_s[e];
        float2 v = *(const float2*)(t2 + (size_t)s * 2);
        a0 += w * v.x;
        a1 += w * v.y;
    }
    out[(size_t)node * 2 + 0] = a0 + b3[0];
    out[(size_t)node * 2 + 1] = a1 + b3[1];
}

// ---------------- launch ----------------

extern "C" void kernel_launch(void* const* d_in, const int* in_sizes, int n_in,
                              void* d_out, int out_size, void* d_ws, size_t ws_size,
                              hipStream_t stream) {
    const int N = N_NODES, E = N_EDGES;
    const float* x  = (const float*)d_in[0];
    const int* ei   = (const int*)d_in[1];
    const int* esrc = ei;       // edge_index[0]
    const int* edst = ei + E;   // edge_index[1]
    const float* W0 = (const float*)d_in[2];
    const float* b0 = (const float*)d_in[3];
    const float* W1 = (const float*)d_in[4];
    const float* b1 = (const float*)d_in[5];
    const float* W2 = (const float*)d_in[6];
    const float* b2 = (const float*)d_in[7];
    const float* W3 = (const float*)d_in[8];
    const float* b3 = (const float*)d_in[9];
    float* out = (float*)d_out;

    // workspace carve
    float* A      = (float*)d_ws;                   // N*256
    float* B      = A + (size_t)N * 256;            // N*256
    float* t2     = B + (size_t)N * 256;            // N*2
    float* dis    = t2 + (size_t)N * 2;             // N
    float* norm_s = dis + N;                        // E+N
    int*   cnt    = (int*)(norm_s + (E + N));       // N
    int*   row_ptr= cnt + N;                        // N+1
    int*   pos    = row_ptr + (N + 1);              // N
    int*   src_s  = pos + N;                        // E+N
    int*   blk    = src_s + (E + N);                // cdiv(N,1024)

    const int NB = cdiv(N, 1024);

    // CSR build
    k_init_cnt<<<cdiv(N, 256), 256, 0, stream>>>(cnt, N);
    k_count<<<cdiv(E, 256), 256, 0, stream>>>(edst, cnt, E);
    k_scan1<<<NB, 256, 0, stream>>>(cnt, row_ptr, dis, blk, N);
    k_scan2<<<1, 256, 0, stream>>>(blk, row_ptr + N, NB);
    k_scan3<<<NB, 256, 0, stream>>>(row_ptr, pos, blk, N);
    k_fill_self<<<cdiv(N, 256), 256, 0, stream>>>(pos, dis, src_s, norm_s, N);
    k_fill_edges<<<cdiv(E, 256), 256, 0, stream>>>(esrc, edst, pos, dis, src_s, norm_s, E);

    dim3 ggrid(cdiv(N, 64), 4);
    int agrid = cdiv(N, 4);

    // layer 0
    k_gemm256<<<ggrid, 256, 0, stream>>>(x, W0, A, N);
    k_agg256<<<agrid, 256, 0, stream>>>(A, row_ptr, src_s, norm_s, b0, B, N, 1);
    // layer 1
    k_gemm256<<<ggrid, 256, 0, stream>>>(B, W1, A, N);
    k_agg256<<<agrid, 256, 0, stream>>>(A, row_ptr, src_s, norm_s, b1, B, N, 1);
    // layer 2
    k_gemm256<<<ggrid, 256, 0, stream>>>(B, W2, A, N);
    k_agg256<<<agrid, 256, 0, stream>>>(A, row_ptr, src_s, norm_s, b2, B, N, 1);
    // layer 3 (no relu)
    k_gemm_out2<<<agrid, 256, 0, stream>>>(B, W3, t2, N);
    k_agg2<<<cdiv(N, 256), 256, 0, stream>>>(t2, row_ptr, src_s, norm_s, b3, out, N);
}

// Round 3
// 656.974 us; speedup vs baseline: 1.4594x; 1.2821x over previous
//
#include <hip/hip_runtime.h>

#define N_NODES 50000
#define N_EDGES 800000
// dims: IN=HID=256, OUT=2

static inline int cdiv(int a, int b) { return (a + b - 1) / b; }

static __device__ __forceinline__ unsigned short f2bf(float f) {
    unsigned int u = __float_as_uint(f);
    unsigned int r = (u + 0x7FFF + ((u >> 16) & 1)) >> 16;  // round-to-nearest-even
    return (unsigned short)r;
}
static __device__ __forceinline__ float bf_lo(unsigned int u) {  // low ushort -> float
    return __uint_as_float(u << 16);
}
static __device__ __forceinline__ float bf_hi(unsigned int u) {  // high ushort -> float
    return __uint_as_float(u & 0xFFFF0000u);
}

// ---------------- CSR build ----------------

__global__ void k_init_cnt(int* cnt, int n) {
    int i = blockIdx.x * 256 + threadIdx.x;
    if (i < n) cnt[i] = 1;  // self-loop
}

__global__ void k_count(const int* __restrict__ edst, int* cnt, int e) {
    int i = blockIdx.x * 256 + threadIdx.x;
    if (i < e) atomicAdd(&cnt[edst[i]], 1);
}

// hierarchical scan: pass 1 — per-block (1024 elems) exclusive scan + block totals
__global__ __launch_bounds__(256) void k_scan1(const int* __restrict__ cnt,
                                               int* __restrict__ row_ptr,
                                               float* __restrict__ dis,
                                               int* __restrict__ blk, int n) {
    __shared__ int sums[256];
    int t = threadIdx.x;
    int base = blockIdx.x * 1024 + t * 4;
    int c0 = 0, c1 = 0, c2 = 0, c3 = 0;
    if (base + 3 < n) {
        int4 v = *(const int4*)(cnt + base);
        c0 = v.x; c1 = v.y; c2 = v.z; c3 = v.w;
    } else {
        if (base + 0 < n) c0 = cnt[base + 0];
        if (base + 1 < n) c1 = cnt[base + 1];
        if (base + 2 < n) c2 = cnt[base + 2];
        if (base + 3 < n) c3 = cnt[base + 3];
    }
    int s = c0 + c1 + c2 + c3;
    sums[t] = s;
    __syncthreads();
    int x = s;
    for (int off = 1; off < 256; off <<= 1) {
        int y = (t >= off) ? sums[t - off] : 0;
        __syncthreads();
        x += y;
        sums[t] = x;
        __syncthreads();
    }
    int excl = x - s;  // exclusive prefix within block
    if (base + 0 < n) { row_ptr[base + 0] = excl;                dis[base + 0] = rsqrtf((float)c0); }
    if (base + 1 < n) { row_ptr[base + 1] = excl + c0;           dis[base + 1] = rsqrtf((float)c1); }
    if (base + 2 < n) { row_ptr[base + 2] = excl + c0 + c1;      dis[base + 2] = rsqrtf((float)c2); }
    if (base + 3 < n) { row_ptr[base + 3] = excl + c0 + c1 + c2; dis[base + 3] = rsqrtf((float)c3); }
    if (t == 255) blk[blockIdx.x] = x;  // block total
}

// pass 2 — scan block totals (nb <= 256), write grand total to row_ptr[n]
__global__ __launch_bounds__(256) void k_scan2(int* __restrict__ blk,
                                               int* __restrict__ row_ptr_n, int nb) {
    __shared__ int sums[256];
    int t = threadIdx.x;
    int s = (t < nb) ? blk[t] : 0;
    sums[t] = s;
    __syncthreads();
    int x = s;
    for (int off = 1; off < 256; off <<= 1) {
        int y = (t >= off) ? sums[t - off] : 0;
        __syncthreads();
        x += y;
        sums[t] = x;
        __syncthreads();
    }
    if (t < nb) blk[t] = x - s;  // exclusive
    if (t == 255) row_ptr_n[0] = x;  // grand total
}

// pass 3 — add block offsets, emit pos copy
__global__ __launch_bounds__(256) void k_scan3(int* __restrict__ row_ptr,
                                               int* __restrict__ pos,
                                               const int* __restrict__ blk, int n) {
    int base = blockIdx.x * 1024 + threadIdx.x * 4;
    int off = blk[blockIdx.x];
#pragma unroll
    for (int i = 0; i < 4; ++i) {
        int idx = base + i;
        if (idx < n) {
            int v = row_ptr[idx] + off;
            row_ptr[idx] = v;
            pos[idx] = v;
        }
    }
}

__global__ void k_fill_self(int* pos, const float* __restrict__ dis,
                            int* src_s, float* norm_s, int n) {
    int i = blockIdx.x * 256 + threadIdx.x;
    if (i < n) {
        int p = atomicAdd(&pos[i], 1);
        src_s[p] = i;
        float d = dis[i];
        norm_s[p] = d * d;
    }
}

__global__ void k_fill_edges(const int* __restrict__ esrc, const int* __restrict__ edst,
                             int* pos, const float* __restrict__ dis,
                             int* src_s, float* norm_s, int e) {
    int i = blockIdx.x * 256 + threadIdx.x;
    if (i < e) {
        int s = esrc[i], d = edst[i];
        int p = atomicAdd(&pos[d], 1);
        src_s[p] = s;
        norm_s[p] = dis[s] * dis[d];
    }
}

// ---------------- GEMM [M,256] @ [256,256] -> bf16 [M,256] ----------------

__global__ __launch_bounds__(256) void k_gemm256(const float* __restrict__ A,
                                                 const float* __restrict__ W,
                                                 unsigned short* __restrict__ C, int M) {
    __shared__ float As[16][64];  // [k][m] transposed
    __shared__ float Bs[16][64];  // [k][n]
    int t = threadIdx.x;
    int m0 = blockIdx.x * 64;
    int n0 = blockIdx.y * 64;
    int tr = t >> 4;          // 0..15 -> rows tr*4..+3
    int tc = t & 15;          // 0..15 -> cols tc*4..+3
    float acc[4][4] = {};

    int arow = t >> 2;        // 0..63
    int acol = (t & 3) * 4;   // 0,4,8,12
    int am = m0 + arow; if (am >= M) am = M - 1;  // clamp; store is guarded
    const float* Aptr = A + (size_t)am * 256 + acol;
    int brow = t >> 4;        // 0..15
    int bcol = (t & 15) * 4;  // 0..60
    const float* Wptr = W + (size_t)brow * 256 + n0 + bcol;

    for (int k0 = 0; k0 < 256; k0 += 16) {
        float4 av = *(const float4*)(Aptr + k0);
        float4 bv = *(const float4*)(Wptr + (size_t)k0 * 256);
        __syncthreads();
        As[acol + 0][arow] = av.x;
        As[acol + 1][arow] = av.y;
        As[acol + 2][arow] = av.z;
        As[acol + 3][arow] = av.w;
        *(float4*)&Bs[brow][bcol] = bv;
        __syncthreads();
#pragma unroll
        for (int k = 0; k < 16; ++k) {
            float a0 = As[k][tr * 4 + 0];
            float a1 = As[k][tr * 4 + 1];
            float a2 = As[k][tr * 4 + 2];
            float a3 = As[k][tr * 4 + 3];
            float b0 = Bs[k][tc * 4 + 0];
            float b1 = Bs[k][tc * 4 + 1];
            float b2 = Bs[k][tc * 4 + 2];
            float b3 = Bs[k][tc * 4 + 3];
            acc[0][0] += a0 * b0; acc[0][1] += a0 * b1; acc[0][2] += a0 * b2; acc[0][3] += a0 * b3;
            acc[1][0] += a1 * b0; acc[1][1] += a1 * b1; acc[1][2] += a1 * b2; acc[1][3] += a1 * b3;
            acc[2][0] += a2 * b0; acc[2][1] += a2 * b1; acc[2][2] += a2 * b2; acc[2][3] += a2 * b3;
            acc[3][0] += a3 * b0; acc[3][1] += a3 * b1; acc[3][2] += a3 * b2; acc[3][3] += a3 * b3;
        }
    }
#pragma unroll
    for (int i = 0; i < 4; ++i) {
        int m = m0 + tr * 4 + i;
        if (m < M) {
            ushort4 sv;
            sv.x = f2bf(acc[i][0]); sv.y = f2bf(acc[i][1]);
            sv.z = f2bf(acc[i][2]); sv.w = f2bf(acc[i][3]);
            *(ushort4*)(C + (size_t)m * 256 + n0 + tc * 4) = sv;
        }
    }
}

// ---------------- aggregation dim=256 over bf16 messages ----------------
// wave per node; half-wave (32 lanes) per edge: lane handles features 8*(lane&31)..+7
// half 0 processes even edge offsets, half 1 odd; combine via shfl_xor(32).

__global__ __launch_bounds__(256) void k_agg256(const unsigned short* __restrict__ t,
                                                const int* __restrict__ row_ptr,
                                                const int* __restrict__ src_s,
                                                const float* __restrict__ norm_s,
                                                const float* __restrict__ bias,
                                                float* __restrict__ out, int n, int relu) {
    int lane = threadIdx.x & 63;
    int wave = threadIdx.x >> 6;
    int node = blockIdx.x * 4 + wave;
    if (node >= n) return;
    int half = lane >> 5;
    int fl = lane & 31;             // feature group: 8*fl .. 8*fl+7
    int beg = row_ptr[node], end = row_ptr[node + 1];
    float acc[8] = {};
    const unsigned short* tp = t + fl * 8;

    int e = beg + half;
    for (; e + 2 < end; e += 4) {
        int s0 = src_s[e], s1 = src_s[e + 2];
        float w0 = norm_s[e], w1 = norm_s[e + 2];
        uint4 v0 = *(const uint4*)(tp + (size_t)s0 * 256);
        uint4 v1 = *(const uint4*)(tp + (size_t)s1 * 256);
        acc[0] += w0 * bf_lo(v0.x) + w1 * bf_lo(v1.x);
        acc[1] += w0 * bf_hi(v0.x) + w1 * bf_hi(v1.x);
        acc[2] += w0 * bf_lo(v0.y) + w1 * bf_lo(v1.y);
        acc[3] += w0 * bf_hi(v0.y) + w1 * bf_hi(v1.y);
        acc[4] += w0 * bf_lo(v0.z) + w1 * bf_lo(v1.z);
        acc[5] += w0 * bf_hi(v0.z) + w1 * bf_hi(v1.z);
        acc[6] += w0 * bf_lo(v0.w) + w1 * bf_lo(v1.w);
        acc[7] += w0 * bf_hi(v0.w) + w1 * bf_hi(v1.w);
    }
    if (e < end) {
        int s0 = src_s[e];
        float w0 = norm_s[e];
        uint4 v0 = *(const uint4*)(tp + (size_t)s0 * 256);
        acc[0] += w0 * bf_lo(v0.x);
        acc[1] += w0 * bf_hi(v0.x);
        acc[2] += w0 * bf_lo(v0.y);
        acc[3] += w0 * bf_hi(v0.y);
        acc[4] += w0 * bf_lo(v0.z);
        acc[5] += w0 * bf_hi(v0.z);
        acc[6] += w0 * bf_lo(v0.w);
        acc[7] += w0 * bf_hi(v0.w);
    }
#pragma unroll
    for (int i = 0; i < 8; ++i) acc[i] += __shfl_xor(acc[i], 32);

    if (half == 0) {
        const float* bp = bias + fl * 8;
#pragma unroll
        for (int i = 0; i < 8; ++i) {
            float v = acc[i] + bp[i];
            if (relu) v = v > 0.f ? v : 0.f;
            acc[i] = v;
        }
        float* op = out + (size_t)node * 256 + fl * 8;
        *(float4*)(op + 0) = make_float4(acc[0], acc[1], acc[2], acc[3]);
        *(float4*)(op + 4) = make_float4(acc[4], acc[5], acc[6], acc[7]);
    }
}

// ---------------- final projection [N,256]@[256,2] (wave per row) ----------------

__global__ __launch_bounds__(256) void k_gemm_out2(const float* __restrict__ h,
                                                   const float* __restrict__ W3,
                                                   float* __restrict__ t2, int n) {
    int lane = threadIdx.x & 63;
    int wave = threadIdx.x >> 6;
    int row = blockIdx.x * 4 + wave;
    if (row >= n) return;
    float4 v = *(const float4*)(h + (size_t)row * 256 + lane * 4);
    float4 w01 = *(const float4*)(W3 + lane * 8);
    float4 w23 = *(const float4*)(W3 + lane * 8 + 4);
    float s0 = v.x * w01.x + v.y * w01.z + v.z * w23.x + v.w * w23.z;
    float s1 = v.x * w01.y + v.y * w01.w + v.z * w23.y + v.w * w23.w;
#pragma unroll
    for (int off = 32; off > 0; off >>= 1) {
        s0 += __shfl_down(s0, off);
        s1 += __shfl_down(s1, off);
    }
    if (lane == 0) {
        t2[(size_t)row * 2 + 0] = s0;
        t2[(size_t)row * 2 + 1] = s1;
    }
}

__global__ void k_agg2(const float* __restrict__ t2,
                       const int* __restrict__ row_ptr,
                       const int* __restrict__ src_s,
                       const float* __restrict__ norm_s,
                       const float* __restrict__ b3,
                       float* __restrict__ out, int n) {
    int node = blockIdx.x * 256 + threadIdx.x;
    if (node >= n) return;
    int beg = row_ptr[node], end = row_ptr[node + 1];
    float a0 = 0.f, a1 = 0.f;
    for (int e = beg; e < end; ++e) {
        int s = src_s[e];
        float w = norm_s[e];
        float2 v = *(const float2*)(t2 + (size_t)s * 2);
        a0 += w * v.x;
        a1 += w * v.y;
    }
    out[(size_t)node * 2 + 0] = a0 + b3[0];
    out[(size_t)node * 2 + 1] = a1 + b3[1];
}

// ---------------- launch ----------------

extern "C" void kernel_launch(void* const* d_in, const int* in_sizes, int n_in,
                              void* d_out, int out_size, void* d_ws, size_t ws_size,
                              hipStream_t stream) {
    const int N = N_NODES, E = N_EDGES;
    const float* x  = (const float*)d_in[0];
    const int* ei   = (const int*)d_in[1];
    const int* esrc = ei;       // edge_index[0]
    const int* edst = ei + E;   // edge_index[1]
    const float* W0 = (const float*)d_in[2];
    const float* b0 = (const float*)d_in[3];
    const float* W1 = (const float*)d_in[4];
    const float* b1 = (const float*)d_in[5];
    const float* W2 = (const float*)d_in[6];
    const float* b2 = (const float*)d_in[7];
    const float* W3 = (const float*)d_in[8];
    const float* b3 = (const float*)d_in[9];
    float* out = (float*)d_out;

    // workspace carve (A region sized as fp32 but holds bf16 messages)
    float* A      = (float*)d_ws;                   // N*256 (bf16 used: first half)
    float* B      = A + (size_t)N * 256;            // N*256 fp32
    float* t2     = B + (size_t)N * 256;            // N*2
    float* dis    = t2 + (size_t)N * 2;             // N
    float* norm_s = dis + N;                        // E+N
    int*   cnt    = (int*)(norm_s + (E + N));       // N
    int*   row_ptr= cnt + N;                        // N+1
    int*   pos    = row_ptr + (N + 1);              // N
    int*   src_s  = pos + N;                        // E+N
    int*   blk    = src_s + (E + N);                // cdiv(N,1024)
    unsigned short* Tb = (unsigned short*)A;        // bf16 message tensor

    const int NB = cdiv(N, 1024);

    // CSR build
    k_init_cnt<<<cdiv(N, 256), 256, 0, stream>>>(cnt, N);
    k_count<<<cdiv(E, 256), 256, 0, stream>>>(edst, cnt, E);
    k_scan1<<<NB, 256, 0, stream>>>(cnt, row_ptr, dis, blk, N);
    k_scan2<<<1, 256, 0, stream>>>(blk, row_ptr + N, NB);
    k_scan3<<<NB, 256, 0, stream>>>(row_ptr, pos, blk, N);
    k_fill_self<<<cdiv(N, 256), 256, 0, stream>>>(pos, dis, src_s, norm_s, N);
    k_fill_edges<<<cdiv(E, 256), 256, 0, stream>>>(esrc, edst, pos, dis, src_s, norm_s, E);

    dim3 ggrid(cdiv(N, 64), 4);
    int agrid = cdiv(N, 4);

    // layer 0
    k_gemm256<<<ggrid, 256, 0, stream>>>(x, W0, Tb, N);
    k_agg256<<<agrid, 256, 0, stream>>>(Tb, row_ptr, src_s, norm_s, b0, B, N, 1);
    // layer 1
    k_gemm256<<<ggrid, 256, 0, stream>>>(B, W1, Tb, N);
    k_agg256<<<agrid, 256, 0, stream>>>(Tb, row_ptr, src_s, norm_s, b1, B, N, 1);
    // layer 2
    k_gemm256<<<ggrid, 256, 0, stream>>>(B, W2, Tb, N);
    k_agg256<<<agrid, 256, 0, stream>>>(Tb, row_ptr, src_s, norm_s, b2, B, N, 1);
    // layer 3 (no relu)
    k_gemm_out2<<<agrid, 256, 0, stream>>>(B, W3, t2, N);
    k_agg2<<<cdiv(N, 256), 256, 0, stream>>>(t2, row_ptr, src_s, norm_s, b3, out, N);
}